// Round 10
// baseline (168.219 us; speedup 1.0000x reference)
//
#include <hip/hip_runtime.h>

#define W 144
#define PLANE (W * W)
#define VOL (W * W * W)
#define NB 2
#define WIN 11
#define PAD 5
#define YCHUNKS 8
#define YC (W / YCHUNKS)       // 18
#define XSEG 3
#define XW 48                  // x outputs per wave
#define ZCHUNKS 3
#define ZCHUNK (W / ZCHUNKS)   // 48
#define NCELL 256
#define WPB 4                  // waves per block

// One scan step: x += dpp_shift(x), with old=0 so invalid/masked lanes add 0.
template <int CTRL, int RM>
__device__ __forceinline__ float dpp_sum_step(float x) {
    const int y = __builtin_amdgcn_update_dpp(0, __float_as_int(x), CTRL, RM, 0xf, false);
    return x + __int_as_float(y);
}

// 64-lane inclusive scan in registers (VALU pipe only).
__device__ __forceinline__ float wave_iscan(float x) {
    x = dpp_sum_step<0x111, 0xf>(x);  // row_shr:1
    x = dpp_sum_step<0x112, 0xf>(x);  // row_shr:2
    x = dpp_sum_step<0x114, 0xf>(x);  // row_shr:4
    x = dpp_sum_step<0x118, 0xf>(x);  // row_shr:8
    x = dpp_sum_step<0x142, 0xa>(x);  // row_bcast:15 -> rows 1,3
    x = dpp_sum_step<0x143, 0xc>(x);  // row_bcast:31 -> rows 2,3
    return x;
}

// 11-tap window sum: win_j = S[j+10] - S[j-1].
__device__ __forceinline__ float win11(float x, int bp_addr) {
    const float S = wave_iscan(x);
    const int sm1 = __builtin_amdgcn_update_dpp(0, __float_as_int(S), 0x138, 0xf, 0xf, false);
    const float sp10 = __int_as_float(
        __builtin_amdgcn_ds_bpermute(bp_addr, __float_as_int(S)));
    return sp10 - __int_as_float(sm1);
}

// ---------- shared body for k12 and its probes ----------
// MODE 0: real (stores to ws). MODE 1: no stores (asm sink). MODE 2: dummy
// fixed-address store per lane (L2-resident) with identical guards/counts.
template <int MODE>
__device__ __forceinline__ void
k12_body(const float* __restrict__ pred, const float* __restrict__ targ,
         float4* __restrict__ ws, double* __restrict__ accL1,
         float4* __restrict__ dum) {
    const int tid = threadIdx.x;
    const int l = tid & 63;
    const int wid = tid >> 6;
    int wg = blockIdx.x * WPB + wid;
    const int gw = wg;                 // global wave id
    const int xs = wg % XSEG; wg /= XSEG;
    const int yc = wg % YCHUNKS; wg /= YCHUNKS;
    const int z = wg % W; wg /= W;
    const int b = wg;
    const int y0 = yc * YC;

    const int x_in = xs * XW - PAD + l;
    const bool vload = (l < XW + 2 * PAD) && (x_in >= 0) && (x_in < W);
    const int xg = (x_in < 0) ? 0 : ((x_in >= W) ? (W - 1) : x_in);
    const size_t base = (size_t)b * VOL + (size_t)z * PLANE + xg;

    const int bp_addr = ((l + (WIN - 1)) & 63) << 2;
    const bool lown = (l >= PAD) && (l < PAD + XW);

    float r0[WIN], r1[WIN], r2[WIN], r3[WIN];
    float s40 = 0.f, s41 = 0.f, s42 = 0.f, s43 = 0.f;
#pragma unroll
    for (int k = 0; k < WIN; ++k) { r0[k] = 0.f; r1[k] = 0.f; r2[k] = 0.f; r3[k] = 0.f; }
    float l1 = 0.f;

    const int yl_start = (y0 >= PAD) ? (y0 - PAD) : 0;
    const int yl_end = y0 + YC + PAD;
    const int nsteps = yl_end - yl_start;      // 23 or 28

    float p0 = 0.f, t0 = 0.f, p1 = 0.f, t1 = 0.f;
    if (vload) {
        if (yl_start < W) {
            p0 = pred[base + (size_t)yl_start * W];
            t0 = targ[base + (size_t)yl_start * W];
        }
        if (yl_start + 1 < W && yl_start + 1 < yl_end) {
            p1 = pred[base + (size_t)(yl_start + 1) * W];
            t1 = targ[base + (size_t)(yl_start + 1) * W];
        }
    }

    for (int c = 0; c < 3; ++c) {
#pragma unroll
        for (int u = 0; u < WIN; ++u) {
            const int i = c * WIN + u;
            if (i < nsteps) {  // wave-uniform
                const int yl = yl_start + i;
                const float p = p0, t = t0;
                p0 = p1; t0 = t1;
                p1 = 0.f; t1 = 0.f;
                const int yn = yl + 2;
                if (vload && yn < W && yn < yl_end) {
                    p1 = pred[base + (size_t)yn * W];
                    t1 = targ[base + (size_t)yn * W];
                }

                const bool rown = (yl >= y0) && (yl < y0 + YC);
                l1 += (rown && lown) ? fabsf(p - t) : 0.f;

                const float vpt = p * t;
                const float vsq = fmaf(p, p, t * t);
                const float w0 = win11(p, bp_addr);
                const float w1 = win11(t, bp_addr);
                const float w2 = win11(vpt, bp_addr);
                const float w3 = win11(vsq, bp_addr);

                s40 += w0 - r0[u]; r0[u] = w0;
                s41 += w1 - r1[u]; r1[u] = w1;
                s42 += w2 - r2[u]; r2[u] = w2;
                s43 += w3 - r3[u]; r3[u] = w3;

                const int y_out = yl - PAD;
                if (y_out >= y0 && l < XW) {
                    if (MODE == 0) {
                        const size_t o = (size_t)b * VOL + (size_t)z * PLANE +
                                         (size_t)y_out * W + (xs * XW + l);
                        ws[o] = make_float4(s40, s41, s42, s43);
                    } else if (MODE == 2) {
                        dum[(size_t)gw * 64 + l] = make_float4(s40, s41, s42, s43);
                    }
                }
            }
        }
    }

    if (MODE == 0) {
        l1 += __shfl_xor(l1, 32);
        l1 += __shfl_xor(l1, 16);
        l1 += __shfl_xor(l1, 8);
        l1 += __shfl_xor(l1, 4);
        l1 += __shfl_xor(l1, 2);
        l1 += __shfl_xor(l1, 1);
        if (l == 0) atomicAdd(&accL1[(blockIdx.x * WPB + wid) & (NCELL - 1)], (double)l1);
    } else {
        // keep the whole chain live without writing anything
        asm volatile("" :: "v"(s40), "v"(s41), "v"(s42), "v"(s43), "v"(l1));
    }
}

__global__ __launch_bounds__(WPB * 64) void
k12_xypass(const float* __restrict__ pred, const float* __restrict__ targ,
           float4* __restrict__ ws, double* __restrict__ accL1) {
    k12_body<0>(pred, targ, ws, accL1, nullptr);
}

__global__ __launch_bounds__(WPB * 64) void
p1_nostore(const float* __restrict__ pred, const float* __restrict__ targ,
           float4* __restrict__ ws, double* __restrict__ accL1) {
    k12_body<1>(pred, targ, ws, accL1, nullptr);
}

__global__ __launch_bounds__(WPB * 64) void
p0_dumstore(const float* __restrict__ pred, const float* __restrict__ targ,
            float4* __restrict__ ws, double* __restrict__ accL1,
            float4* __restrict__ dum) {
    k12_body<2>(pred, targ, ws, accL1, dum);
}

// K3: z-window running sum (static ring) over the float4 field stream + SSIM.
__global__ void k3_zpass(const float4* __restrict__ ws, double* __restrict__ accS) {
    const int x = threadIdx.x;
    int bid = blockIdx.x;
    const int c = bid % ZCHUNKS; bid /= ZCHUNKS;
    const int y = bid % W; bid /= W;
    const int b = bid;
    const int zstart = c * ZCHUNK;

    const float4* F = ws + (size_t)b * VOL + (size_t)y * W + x;

    float r0[WIN], r1[WIN], r2[WIN], r3[WIN];
    float s0 = 0.f, s1 = 0.f, s2 = 0.f, s3 = 0.f;
#pragma unroll
    for (int k = 0; k < WIN; ++k) { r0[k] = 0.f; r1[k] = 0.f; r2[k] = 0.f; r3[k] = 0.f; }

    const float inv = 1.0f / 1331.0f;
    const float C1 = 0.01f * 0.01f;
    const float C2 = 0.03f * 0.03f;
    float ssim_acc = 0.f;

    const int NSTEP = ZCHUNK + 2 * PAD;  // 58
    for (int cc = 0; cc < 6; ++cc) {
#pragma unroll
        for (int u = 0; u < WIN; ++u) {
            const int i = cc * WIN + u;
            if (i < NSTEP) {
                const int zl = zstart - PAD + i;
                float4 v = make_float4(0.f, 0.f, 0.f, 0.f);
                if (zl >= 0 && zl < W) v = F[(size_t)zl * PLANE];
                s0 += v.x - r0[u]; r0[u] = v.x;
                s1 += v.y - r1[u]; r1[u] = v.y;
                s2 += v.z - r2[u]; r2[u] = v.z;
                s3 += v.w - r3[u]; r3[u] = v.w;
                if (i >= 2 * PAD) {
                    const float mu_p = s0 * inv;
                    const float mu_t = s1 * inv;
                    const float ept = s2 * inv;
                    const float esq = s3 * inv;
                    const float mupt = mu_p * mu_t;
                    const float musq = mu_p * mu_p + mu_t * mu_t;
                    const float sig_pt = ept - mupt;
                    const float sigsum = esq - musq;
                    const float num = (2.f * mupt + C1) * (2.f * sig_pt + C2);
                    const float den = (musq + C1) * (sigsum + C2);
                    ssim_acc += num / den;
                }
            }
        }
    }

    __shared__ float red[W];
    red[x] = ssim_acc;
    __syncthreads();
    if (x < 16) {
        float s2r = 0.f;
#pragma unroll
        for (int k = 0; k < 9; ++k) s2r += red[x + 16 * k];
        s2r += __shfl_down(s2r, 8);
        s2r += __shfl_down(s2r, 4);
        s2r += __shfl_down(s2r, 2);
        s2r += __shfl_down(s2r, 1);
        if (x == 0) atomicAdd(&accS[blockIdx.x & (NCELL - 1)], (double)s2r);
    }
}

// K4: reduce the 2x256 cells, write the 3 outputs.
__global__ void k4_final(const double* __restrict__ accL1, const double* __restrict__ accS,
                         float* __restrict__ out) {
    const int x = threadIdx.x;
    __shared__ double d1[NCELL];
    __shared__ double d2[NCELL];
    d1[x] = accL1[x];
    d2[x] = accS[x];
    __syncthreads();
    for (int s = NCELL / 2; s > 0; s >>= 1) {
        if (x < s) {
            d1[x] += d1[x + s];
            d2[x] += d2[x + s];
        }
        __syncthreads();
    }
    if (x == 0) {
        const double n = (double)NB * (double)VOL;
        const double l1 = d1[0] / n;
        const double ssim_loss = 1.0 - d2[0] / n;
        const double total = l1 + 0.5 * ssim_loss;
        out[0] = (float)total;
        out[1] = (float)l1;
        out[2] = (float)ssim_loss;
    }
}

extern "C" void kernel_launch(void* const* d_in, const int* in_sizes, int n_in,
                              void* d_out, int out_size, void* d_ws, size_t ws_size,
                              hipStream_t stream) {
    const float* pred = (const float*)d_in[0];
    const float* targ = (const float*)d_in[1];
    float* out = (float*)d_out;
    float4* ws = (float4*)d_ws;
    double* accL1 = (double*)((char*)d_ws + (size_t)NB * VOL * sizeof(float4));
    double* accS = accL1 + NCELL;
    float4* dum = (float4*)((char*)d_ws + (size_t)NB * VOL * sizeof(float4) +
                            4096);  // probe scratch, past the acc cells

    const int nwaves = NB * W * YCHUNKS * XSEG;  // 6912
    hipMemsetAsync(accL1, 0, 2 * NCELL * sizeof(double), stream);

    // ---- diagnostic probes (results discarded; ws overwritten by real pass) ----
    p1_nostore<<<nwaves / WPB, WPB * 64, 0, stream>>>(pred, targ, ws, accL1);
    p0_dumstore<<<nwaves / WPB, WPB * 64, 0, stream>>>(pred, targ, ws, accL1, dum);

    // ---- real pipeline (identical to R6, verified) ----
    k12_xypass<<<nwaves / WPB, WPB * 64, 0, stream>>>(pred, targ, ws, accL1);
    k3_zpass<<<NB * W * ZCHUNKS, W, 0, stream>>>(ws, accS);
    k4_final<<<1, NCELL, 0, stream>>>(accL1, accS, out);
}

// Round 11
// 75.236 us; speedup vs baseline: 2.2359x; 2.2359x over previous
//
#include <hip/hip_runtime.h>

#define W 144
#define PLANE (W * W)
#define VOL (W * W * W)
#define NB 2
#define WIN 11
#define PAD 5
#define YCH 12
#define YC (W / YCH)           // 12
#define NSTEPS (YC + 2 * PAD)  // 22, uniform for every chunk
#define XSEG 3
#define XW 48                  // x outputs per wave
#define ZCH 6
#define ZCL (W / ZCH)          // 24
#define NCELL 256
#define WPB 4                  // waves per block

// One scan step: x += dpp_shift(x), old=0 so invalid/masked lanes add 0.
template <int CTRL, int RM>
__device__ __forceinline__ float dpp_sum_step(float x) {
    const int y = __builtin_amdgcn_update_dpp(0, __float_as_int(x), CTRL, RM, 0xf, false);
    return x + __int_as_float(y);
}

// 64-lane inclusive scan in registers (verified R6, absmax 0).
__device__ __forceinline__ float wave_iscan(float x) {
    x = dpp_sum_step<0x111, 0xf>(x);  // row_shr:1
    x = dpp_sum_step<0x112, 0xf>(x);  // row_shr:2
    x = dpp_sum_step<0x114, 0xf>(x);  // row_shr:4
    x = dpp_sum_step<0x118, 0xf>(x);  // row_shr:8
    x = dpp_sum_step<0x142, 0xa>(x);  // row_bcast:15 -> rows 1,3
    x = dpp_sum_step<0x143, 0xc>(x);  // row_bcast:31 -> rows 2,3
    return x;
}

// 11-tap window over load-lanes j..j+10: win_j = S[j+10] - S[j-1].
__device__ __forceinline__ float win11(float x, int bp_addr) {
    const float S = wave_iscan(x);
    const int sm1 = __builtin_amdgcn_update_dpp(0, __float_as_int(S), 0x138, 0xf, 0xf, false);
    const float sp10 = __int_as_float(
        __builtin_amdgcn_ds_bpermute(bp_addr, __float_as_int(S)));
    return sp10 - __int_as_float(sm1);
}

// K12: fused x+y pass, wave-autonomous, fully-unrolled UNIFORM 22-step loop.
// Wave = (b, z, y-chunk of 12, x-seg of 48). All i-dependent guards fold at
// compile time; only the y-bounds check remains (wave-uniform scalar branch).
__global__ __launch_bounds__(WPB * 64) void
k12_xypass(const float* __restrict__ pred, const float* __restrict__ targ,
           float4* __restrict__ ws, double* __restrict__ accL1) {
    const int tid = threadIdx.x;
    const int l = tid & 63;
    const int wid = tid >> 6;
    int wg = blockIdx.x * WPB + wid;
    const int xs = wg % XSEG; wg /= XSEG;
    const int yc = wg % YCH; wg /= YCH;
    const int z = wg % W; wg /= W;
    const int b = wg;
    const int y0 = yc * YC;

    const int x_in = xs * XW - PAD + l;
    const bool vload = (l < XW + 2 * PAD) && (x_in >= 0) && (x_in < W);
    const int xg = (x_in < 0) ? 0 : ((x_in >= W) ? (W - 1) : x_in);
    const size_t base = (size_t)b * VOL + (size_t)z * PLANE + xg;
    const float* __restrict__ gp = pred + base;
    const float* __restrict__ gt = targ + base;

    const int bp_addr = ((l + (WIN - 1)) & 63) << 2;
    const bool lown = (l >= PAD) && (l < PAD + XW);

    float r0[WIN], r1[WIN], r2[WIN], r3[WIN];
    float s40 = 0.f, s41 = 0.f, s42 = 0.f, s43 = 0.f;
#pragma unroll
    for (int k = 0; k < WIN; ++k) { r0[k] = 0.f; r1[k] = 0.f; r2[k] = 0.f; r3[k] = 0.f; }
    float l1 = 0.f;

    // output pointer for this wave's first output row (i==10 -> y_out = y0)
    float4* __restrict__ orow = ws + (size_t)b * VOL + (size_t)z * PLANE +
                                (size_t)y0 * W + (xs * XW + l);

    // 2-deep prefetch for steps 0,1 (rows y0-5, y0-4)
    float pa = 0.f, ta = 0.f, pn = 0.f, tn = 0.f;
    {
        const int g = y0 - PAD;
        if (g >= 0) {  // uniform
            if (vload) { pa = gp[(size_t)g * W]; ta = gt[(size_t)g * W]; }
        }
        const int g1 = y0 - PAD + 1;
        if (g1 >= 0) {  // uniform
            if (vload) { pn = gp[(size_t)g1 * W]; tn = gt[(size_t)g1 * W]; }
        }
    }

#pragma unroll
    for (int i = 0; i < NSTEPS; ++i) {
        const float p = pa, t = ta;
        pa = pn; ta = tn;
        pn = 0.f; tn = 0.f;
        if (i < NSTEPS - 2) {  // compile-time
            const int g = y0 - PAD + i + 2;
            if (g >= 0 && g < W) {  // wave-uniform runtime branch
                if (vload) { pn = gp[(size_t)g * W]; tn = gt[(size_t)g * W]; }
            }
        }

        if (i >= PAD && i < PAD + YC) {  // compile-time: core rows
            l1 += lown ? fabsf(p - t) : 0.f;
        }

        const float vpt = p * t;
        const float vsq = fmaf(p, p, t * t);
        const float w0 = win11(p, bp_addr);
        const float w1 = win11(t, bp_addr);
        const float w2 = win11(vpt, bp_addr);
        const float w3 = win11(vsq, bp_addr);

        const int u = i % WIN;  // static after unroll
        s40 += w0 - r0[u]; r0[u] = w0;
        s41 += w1 - r1[u]; r1[u] = w1;
        s42 += w2 - r2[u]; r2[u] = w2;
        s43 += w3 - r3[u]; r3[u] = w3;

        if (i >= 2 * PAD) {  // compile-time: output rows
            if (l < XW) {
                orow[(size_t)(i - 2 * PAD) * W] = make_float4(s40, s41, s42, s43);
            }
        }
    }

    // wave-level reduction of l1, one atomic per wave
    l1 += __shfl_xor(l1, 32);
    l1 += __shfl_xor(l1, 16);
    l1 += __shfl_xor(l1, 8);
    l1 += __shfl_xor(l1, 4);
    l1 += __shfl_xor(l1, 2);
    l1 += __shfl_xor(l1, 1);
    if (l == 0) atomicAdd(&accL1[(blockIdx.x * WPB + wid) & (NCELL - 1)], (double)l1);
}

// K3: z-window running sum (static ring) over the float4 field stream + SSIM.
// ZCH=6 for more outstanding columns (latency-bound before).
__global__ void k3_zpass(const float4* __restrict__ ws, double* __restrict__ accS) {
    const int x = threadIdx.x;
    int bid = blockIdx.x;
    const int c = bid % ZCH; bid /= ZCH;
    const int y = bid % W; bid /= W;
    const int b = bid;
    const int zstart = c * ZCL;

    const float4* F = ws + (size_t)b * VOL + (size_t)y * W + x;

    float r0[WIN], r1[WIN], r2[WIN], r3[WIN];
    float s0 = 0.f, s1 = 0.f, s2 = 0.f, s3 = 0.f;
#pragma unroll
    for (int k = 0; k < WIN; ++k) { r0[k] = 0.f; r1[k] = 0.f; r2[k] = 0.f; r3[k] = 0.f; }

    const float inv = 1.0f / 1331.0f;
    const float C1 = 0.01f * 0.01f;
    const float C2 = 0.03f * 0.03f;
    float ssim_acc = 0.f;

    const int NZ = ZCL + 2 * PAD;  // 34
    for (int cc = 0; cc < 4; ++cc) {
#pragma unroll
        for (int u = 0; u < WIN; ++u) {
            const int i = cc * WIN + u;
            if (i < NZ) {
                const int zl = zstart - PAD + i;
                float4 v = make_float4(0.f, 0.f, 0.f, 0.f);
                if (zl >= 0 && zl < W) v = F[(size_t)zl * PLANE];
                s0 += v.x - r0[u]; r0[u] = v.x;
                s1 += v.y - r1[u]; r1[u] = v.y;
                s2 += v.z - r2[u]; r2[u] = v.z;
                s3 += v.w - r3[u]; r3[u] = v.w;
                if (i >= 2 * PAD) {
                    const float mu_p = s0 * inv;
                    const float mu_t = s1 * inv;
                    const float ept = s2 * inv;
                    const float esq = s3 * inv;
                    const float mupt = mu_p * mu_t;
                    const float musq = mu_p * mu_p + mu_t * mu_t;
                    const float sig_pt = ept - mupt;
                    const float sigsum = esq - musq;
                    const float num = (2.f * mupt + C1) * (2.f * sig_pt + C2);
                    const float den = (musq + C1) * (sigsum + C2);
                    ssim_acc += num / den;
                }
            }
        }
    }

    __shared__ float red[W];
    red[x] = ssim_acc;
    __syncthreads();
    if (x < 16) {
        float s2r = 0.f;
#pragma unroll
        for (int k = 0; k < 9; ++k) s2r += red[x + 16 * k];
        s2r += __shfl_down(s2r, 8);
        s2r += __shfl_down(s2r, 4);
        s2r += __shfl_down(s2r, 2);
        s2r += __shfl_down(s2r, 1);
        if (x == 0) atomicAdd(&accS[blockIdx.x & (NCELL - 1)], (double)s2r);
    }
}

// K4: reduce the 2x256 cells, write the 3 outputs.
__global__ void k4_final(const double* __restrict__ accL1, const double* __restrict__ accS,
                         float* __restrict__ out) {
    const int x = threadIdx.x;
    __shared__ double d1[NCELL];
    __shared__ double d2[NCELL];
    d1[x] = accL1[x];
    d2[x] = accS[x];
    __syncthreads();
    for (int s = NCELL / 2; s > 0; s >>= 1) {
        if (x < s) {
            d1[x] += d1[x + s];
            d2[x] += d2[x + s];
        }
        __syncthreads();
    }
    if (x == 0) {
        const double n = (double)NB * (double)VOL;
        const double l1 = d1[0] / n;
        const double ssim_loss = 1.0 - d2[0] / n;
        const double total = l1 + 0.5 * ssim_loss;
        out[0] = (float)total;
        out[1] = (float)l1;
        out[2] = (float)ssim_loss;
    }
}

extern "C" void kernel_launch(void* const* d_in, const int* in_sizes, int n_in,
                              void* d_out, int out_size, void* d_ws, size_t ws_size,
                              hipStream_t stream) {
    const float* pred = (const float*)d_in[0];
    const float* targ = (const float*)d_in[1];
    float* out = (float*)d_out;
    float4* ws = (float4*)d_ws;
    double* accL1 = (double*)((char*)d_ws + (size_t)NB * VOL * sizeof(float4));
    double* accS = accL1 + NCELL;

    hipMemsetAsync(accL1, 0, 2 * NCELL * sizeof(double), stream);
    const int nwaves = NB * W * YCH * XSEG;  // 10368
    k12_xypass<<<nwaves / WPB, WPB * 64, 0, stream>>>(pred, targ, ws, accL1);
    k3_zpass<<<NB * W * ZCH, W, 0, stream>>>(ws, accS);
    k4_final<<<1, NCELL, 0, stream>>>(accL1, accS, out);
}